// Round 8
// baseline (2205.210 us; speedup 1.0000x reference)
//
#include <hip/hip_runtime.h>
#include <math.h>

#define NITER 1000
#define LRATE 0.1f

typedef __fp16 h2 __attribute__((ext_vector_type(2)));
typedef unsigned int v2u __attribute__((ext_vector_type(2)));

__device__ __forceinline__ float rcpf(float x) { return __builtin_amdgcn_rcpf(x); }

__device__ __forceinline__ float readlane_f(float v, int l) {
    return __int_as_float(__builtin_amdgcn_readlane(__float_as_int(v), l));
}

// v_cvt_pkrtz_f16_f32: pack 2 f32 -> h2
__device__ __forceinline__ h2 pkrtz(float a, float b) {
    return __builtin_amdgcn_cvt_pkrtz(a, b);
}

// v_dot2_f32_f16: a.x*b.x + a.y*b.y + c  (f16 inputs, f32 accumulate)
__device__ __forceinline__ float fdot2(h2 a, h2 b, float c) {
    return __builtin_amdgcn_fdot2(a, b, c, false);
}

template<int CTRL>
__device__ __forceinline__ float dpp_mov(float v) {
    return __int_as_float(__builtin_amdgcn_update_dpp(0, __float_as_int(v), CTRL, 0xF, 0xF, true));
}

__device__ __forceinline__ int lane_id() {
    return __builtin_amdgcn_mbcnt_hi(~0u, __builtin_amdgcn_mbcnt_lo(~0u, 0u));
}

__device__ __forceinline__ void swap16(float& x, float& y) {
#if __has_builtin(__builtin_amdgcn_permlane16_swap)
    v2u r = __builtin_amdgcn_permlane16_swap(__float_as_uint(x), __float_as_uint(y), false, false);
    x = __uint_as_float(r[0]);
    y = __uint_as_float(r[1]);
#else
    const bool up = lane_id() & 16;
    const float send = up ? x : y;
    const float recv = __shfl_xor(send, 16);
    x = up ? recv : x;
    y = up ? y : recv;
#endif
}

__device__ __forceinline__ void swap32(float& x, float& y) {
#if __has_builtin(__builtin_amdgcn_permlane32_swap)
    v2u r = __builtin_amdgcn_permlane32_swap(__float_as_uint(x), __float_as_uint(y), false, false);
    x = __uint_as_float(r[0]);
    y = __uint_as_float(r[1]);
#else
    const bool up = lane_id() & 32;
    const float send = up ? x : y;
    const float recv = __shfl_xor(send, 32);
    x = up ? recv : x;
    y = up ? y : recv;
#endif
}

// One block, 1024 threads = 16 waves (4/SIMD). Wave w owns section w; its 6
// coefficients live in registers (owner lanes + readlane broadcast). Lane L
// owns freqs 8L..8L+7. Cross-wave traffic: per-wave |H|^2 partials (wq) and
// per-freq K factors (Kbuf), chunk-swizzled sw = 8L + 4*(L>>2) (2-way = free).
// Forward/grad dots use v_dot2_f32_f16 (f16 inputs, f32 accumulate; 2x rate).
__global__ __launch_bounds__(1024, 4)
void sgd_filter_design_kernel(const float* __restrict__ target,
                              const float* __restrict__ sos_init,
                              float* __restrict__ out)
{
    const int t = threadIdx.x;
    const int w = t >> 6;
    const int L = t & 63;

    __shared__ __align__(16) float wq[16][576];
    __shared__ __align__(16) float Kbuf[576];

    // per-freq f16 constant pairs: hC=(C1,C2), hS=(S1,S2), hP1=(C1,S1), hP2=(C2,S2)
    const float PI = 3.14159265358979323846f;
    h2 hC[8], hS[8], hP1[8], hP2[8];
    #pragma unroll
    for (int f = 0; f < 8; ++f) {
        const int n = 8 * L + f;
        const float wr = PI * (float)n / 511.0f;
        const float c1 = cosf(wr), s1 = sinf(wr);
        const float c2 = 2.0f * c1 * c1 - 1.0f;
        const float s2 = 2.0f * s1 * c1;
        hC[f]  = pkrtz(c1, c2);
        hS[f]  = pkrtz(s1, s2);
        hP1[f] = pkrtz(c1, s1);
        hP2[f] = pkrtz(c2, s2);
    }

    float mKt = 0.0f;
    int kaddr = 0;
    if (t < 512) {
        mKt = -0.03392925639869154f * target[t];          // -ALPHA*tgt
        kaddr = 8 * (t >> 3) + 4 * (t >> 5) + (t & 7);    // swizzled
    }

    const int sw = 8 * L + 4 * (L >> 2);
    const int col = ((L & 16) >> 2) | ((L & 32) >> 4) | (L & 1);
    const bool up1 = L & 1;
    // b-side (col<3): grad accumulated positive -> -=; a-side: true grad is
    // negative of accumulated -> +=.
    const float lrk = (col < 3) ? -LRATE : LRATE;

    float val_own = 0.0f;
    if (col < 6) val_own = sos_init[6 * w + col];

    float B0f = readlane_f(val_own, 0);
    float B1f = readlane_f(val_own, 1);
    float B2f = readlane_f(val_own, 32);
    float A0f = readlane_f(val_own, 33);
    float A1f = readlane_f(val_own, 16);
    float A2f = readlane_f(val_own, 17);

    for (int it = 0; it < NITER; ++it) {
        const h2 hb = pkrtz(B1f, B2f);
        const h2 ha = pkrtz(A1f, A2f);

        // ---- forward: own section at 8 freqs ----
        float Ur[8], Ui[8], Vr[8], Vi[8], qs[8];
        #pragma unroll
        for (int f = 0; f < 8; ++f) {
            const float nr = fdot2(hb, hC[f], B0f);
            const float ni = fdot2(hb, hS[f], 0.0f);   // = -Im(num)
            const float dr = fdot2(ha, hC[f], A0f);
            const float di = fdot2(ha, hS[f], 0.0f);   // = -Im(den)
            const float mn = fmaf(nr, nr, ni * ni);
            const float md = fmaf(dr, dr, di * di);
            const float imn = rcpf(mn);
            const float imd = rcpf(md);
            qs[f] = mn * imd;                           // section |num/den|^2
            Ur[f] = nr * imn; Ui[f] = ni * imn;
            Vr[f] = dr * imd; Vi[f] = di * imd;
        }
        {
            const float4 q0 = {qs[0], qs[1], qs[2], qs[3]};
            const float4 q1 = {qs[4], qs[5], qs[6], qs[7]};
            *reinterpret_cast<float4*>(&wq[w][sw])     = q0;
            *reinterpret_cast<float4*>(&wq[w][sw + 4]) = q1;
        }
        __syncthreads();   // b1: wq ready; fences last iter's Kbuf reads

        // ---- single K-pass: one freq per thread (waves 0-7) ----
        if (t < 512) {
            float p[16];
            #pragma unroll
            for (int ww = 0; ww < 16; ++ww) p[ww] = wq[ww][kaddr];
            p[0] *= p[8];  p[1] *= p[9];  p[2] *= p[10]; p[3] *= p[11];
            p[4] *= p[12]; p[5] *= p[13]; p[6] *= p[14]; p[7] *= p[15];
            p[0] *= p[4];  p[1] *= p[5];  p[2] *= p[6];  p[3] *= p[7];
            p[0] *= p[2];  p[1] *= p[3];
            p[0] *= p[1];
            // K = 0.102137240*log2(q) - ALPHA*tgt
            Kbuf[kaddr] = fmaf(__log2f(p[0]), 0.10213724040f, mKt);
        }
        __syncthreads();   // b2: Kbuf ready

        const float4 k0 = *reinterpret_cast<const float4*>(&Kbuf[sw]);
        const float4 k1 = *reinterpret_cast<const float4*>(&Kbuf[sw + 4]);
        const float Kf[8] = {k0.x, k0.y, k0.z, k0.w, k1.x, k1.y, k1.z, k1.w};

        // ---- gradient accumulate (own section) ----
        float g0 = 0.f, g1 = 0.f, g2 = 0.f, g3 = 0.f, g4 = 0.f, g5 = 0.f;
        #pragma unroll
        for (int f = 0; f < 8; ++f) {
            const float KUr = Kf[f] * Ur[f];
            const float KUi = Kf[f] * Ui[f];
            const float KVr = Kf[f] * Vr[f];
            const float KVi = Kf[f] * Vi[f];
            const h2 hKU = pkrtz(KUr, KUi);
            const h2 hKV = pkrtz(KVr, KVi);
            g0 += KUr;
            g3 += KVr;
            g1 = fdot2(hKU, hP1[f], g1);
            g2 = fdot2(hKU, hP2[f], g2);
            g4 = fdot2(hKV, hP1[f], g4);
            g5 = fdot2(hKV, hP2[f], g5);
        }
        const float g6[6] = {g0, g1, g2, g3, g4, g5};

        // ---- butterfly reduce-scatter: 8 cols (6 real + 2 pad) ----
        float r4v[4];
        #pragma unroll
        for (int i = 0; i < 4; ++i) {            // mask 16, weight 4
            float x = g6[i];
            float y = (i + 4 < 6) ? g6[i + 4] : 0.0f;
            swap16(x, y);
            r4v[i] = x + y;
        }
        float r2v[2];
        #pragma unroll
        for (int i = 0; i < 2; ++i) {            // mask 32, weight 2
            float x = r4v[i], y = r4v[i + 2];
            swap32(x, y);
            r2v[i] = x + y;
        }
        float r1v;
        {                                         // mask 1 (DPP), weight 1
            const float x = r2v[0], y = r2v[1];
            const float P = up1 ? y : x, Q = up1 ? x : y;
            r1v = P + dpp_mov<0xB1>(Q);
        }
        r1v += dpp_mov<0x4E>(r1v);                // mask 2 full sum
        r1v += dpp_mov<0x128>(r1v);               // mask 8 full sum
        r1v += __shfl_xor(r1v, 4);                // mask 4 full sum

        // ---- update + wave-local re-broadcast ----
        val_own = fmaf(lrk, r1v, val_own);
        B0f = readlane_f(val_own, 0);
        B1f = readlane_f(val_own, 1);
        B2f = readlane_f(val_own, 32);
        A0f = readlane_f(val_own, 33);
        A1f = readlane_f(val_own, 16);
        A2f = readlane_f(val_own, 17);
    }

    if ((L & 14) == 0 && col < 6) out[6 * w + col] = val_own;
}

extern "C" void kernel_launch(void* const* d_in, const int* in_sizes, int n_in,
                              void* d_out, int out_size, void* d_ws, size_t ws_size,
                              hipStream_t stream) {
    const float* target   = (const float*)d_in[0];   // (512,)
    const float* sos_init = (const float*)d_in[1];   // (1,16,6) = 96
    float* out = (float*)d_out;                      // 96 floats
    hipLaunchKernelGGL(sgd_filter_design_kernel, dim3(1), dim3(1024), 0, stream,
                       target, sos_init, out);
}

// Round 9
// 1482.141 us; speedup vs baseline: 1.4879x; 1.4879x over previous
//
#include <hip/hip_runtime.h>
#include <math.h>

#define NITER 1000
#define LRATE 0.1f

typedef unsigned int v2u __attribute__((ext_vector_type(2)));

__device__ __forceinline__ float rcpf(float x) { return __builtin_amdgcn_rcpf(x); }

__device__ __forceinline__ float readlane_f(float v, int l) {
    return __int_as_float(__builtin_amdgcn_readlane(__float_as_int(v), l));
}

template<int CTRL>
__device__ __forceinline__ float dpp_mov(float v) {
    return __int_as_float(__builtin_amdgcn_update_dpp(0, __float_as_int(v), CTRL, 0xF, 0xF, true));
}

__device__ __forceinline__ int lane_id() {
    return __builtin_amdgcn_mbcnt_hi(~0u, __builtin_amdgcn_mbcnt_lo(~0u, 0u));
}

__device__ __forceinline__ void swap16(float& x, float& y) {
#if __has_builtin(__builtin_amdgcn_permlane16_swap)
    v2u r = __builtin_amdgcn_permlane16_swap(__float_as_uint(x), __float_as_uint(y), false, false);
    x = __uint_as_float(r[0]);
    y = __uint_as_float(r[1]);
#else
    const bool up = lane_id() & 16;
    const float send = up ? x : y;
    const float recv = __shfl_xor(send, 16);
    x = up ? recv : x;
    y = up ? y : recv;
#endif
}

__device__ __forceinline__ void swap32(float& x, float& y) {
#if __has_builtin(__builtin_amdgcn_permlane32_swap)
    v2u r = __builtin_amdgcn_permlane32_swap(__float_as_uint(x), __float_as_uint(y), false, false);
    x = __uint_as_float(r[0]);
    y = __uint_as_float(r[1]);
#else
    const bool up = lane_id() & 32;
    const float send = up ? x : y;
    const float recv = __shfl_xor(send, 32);
    x = up ? recv : x;
    y = up ? y : recv;
#endif
}

// One block, 1024 threads = 16 waves (4/SIMD). Wave w owns section w; all 6
// of its coefficients are wave-uniform scalars. Lane L owns freqs 8L..8L+7.
// Gradient via moment sums: with E=K/|num|^2, F=K/|den|^2 per freq,
//   S0=sum E, S1=sum E*cos(w), S2=sum E*cos(2w)   (T* for the a-side)
//   g_b0 = b0*S0 + b1*S1 + b2*S2
//   g_b1 = b1*S0 + (b0+b2)*S1
//   g_b2 = b2*S0 + b1*S1 + b0*S2      (uses cos(w)cos(2w)+sin(w)sin(2w)=cos(w))
// so only 6 values cross lanes; every lane then reconstructs all gradients.
__global__ __launch_bounds__(1024, 4)
void sgd_filter_design_kernel(const float* __restrict__ target,
                              const float* __restrict__ sos_init,
                              float* __restrict__ out)
{
    const int t = threadIdx.x;
    const int w = t >> 6;
    const int L = t & 63;

    __shared__ __align__(16) float wq[16][576];
    __shared__ __align__(16) float Kbuf[576];

    // per-freq constants (f32 scalar)
    const float PI = 3.14159265358979323846f;
    float C1[8], S1[8], C2[8], S2[8];
    #pragma unroll
    for (int f = 0; f < 8; ++f) {
        const int n = 8 * L + f;
        const float wr = PI * (float)n / 511.0f;
        const float c1 = cosf(wr), s1 = sinf(wr);
        C1[f] = c1; S1[f] = s1;
        C2[f] = 2.0f * c1 * c1 - 1.0f;
        S2[f] = 2.0f * s1 * c1;
    }

    float mKt = 0.0f;
    int kaddr = 0;
    if (t < 512) {
        mKt = -0.03392925639869154f * target[t];          // -ALPHA*tgt
        kaddr = 8 * (t >> 3) + 4 * (t >> 5) + (t & 7);    // swizzled
    }

    const int sw = 8 * L + 4 * (L >> 2);                  // 2-way = free
    const int col = ((L & 16) >> 2) | ((L & 32) >> 4) | (L & 1);
    const bool up1 = L & 1;

    // init coefficients as wave-uniform scalars
    float v0 = 0.0f;
    if (col < 6) v0 = sos_init[6 * w + col];
    float B0f = readlane_f(v0, 0);
    float B1f = readlane_f(v0, 1);
    float B2f = readlane_f(v0, 32);
    float A0f = readlane_f(v0, 33);
    float A1f = readlane_f(v0, 16);
    float A2f = readlane_f(v0, 17);

    for (int it = 0; it < NITER; ++it) {
        // ---- forward: own section at 8 freqs ----
        float imn[8], imd[8], qs[8];
        #pragma unroll
        for (int f = 0; f < 8; ++f) {
            const float nr = fmaf(B2f, C2[f], fmaf(B1f, C1[f], B0f));
            const float ni = fmaf(B2f, S2[f], B1f * S1[f]);   // = -Im(num)
            const float dr = fmaf(A2f, C2[f], fmaf(A1f, C1[f], A0f));
            const float di = fmaf(A2f, S2[f], A1f * S1[f]);   // = -Im(den)
            const float mn = fmaf(nr, nr, ni * ni);
            const float md = fmaf(dr, dr, di * di);
            const float rr = rcpf(mn * md);                    // one rcp
            const float iimd = rr * mn;                        // 1/md
            const float iimn = rr * md;                        // 1/mn
            qs[f] = mn * iimd;                                 // |num/den|^2
            imn[f] = iimn;
            imd[f] = iimd;
        }
        {
            const float4 q0 = {qs[0], qs[1], qs[2], qs[3]};
            const float4 q1 = {qs[4], qs[5], qs[6], qs[7]};
            *reinterpret_cast<float4*>(&wq[w][sw])     = q0;
            *reinterpret_cast<float4*>(&wq[w][sw + 4]) = q1;
        }
        __syncthreads();   // b1: wq ready; fences last iter's Kbuf reads

        // ---- single K-pass: one freq per thread (waves 0-7) ----
        if (t < 512) {
            float p[16];
            #pragma unroll
            for (int ww = 0; ww < 16; ++ww) p[ww] = wq[ww][kaddr];
            p[0] *= p[8];  p[1] *= p[9];  p[2] *= p[10]; p[3] *= p[11];
            p[4] *= p[12]; p[5] *= p[13]; p[6] *= p[14]; p[7] *= p[15];
            p[0] *= p[4];  p[1] *= p[5];  p[2] *= p[6];  p[3] *= p[7];
            p[0] *= p[2];  p[1] *= p[3];
            p[0] *= p[1];
            // K = 0.102137240*log2(q) - ALPHA*tgt
            Kbuf[kaddr] = fmaf(__log2f(p[0]), 0.10213724040f, mKt);
        }
        __syncthreads();   // b2: Kbuf ready

        const float4 k0 = *reinterpret_cast<const float4*>(&Kbuf[sw]);
        const float4 k1 = *reinterpret_cast<const float4*>(&Kbuf[sw + 4]);
        const float Kf[8] = {k0.x, k0.y, k0.z, k0.w, k1.x, k1.y, k1.z, k1.w};

        // ---- moment accumulation: 6 sums over own 8 freqs ----
        float X0, X1, X2, X3, X4, X5;
        #pragma unroll
        for (int f = 0; f < 8; ++f) {
            const float E = Kf[f] * imn[f];
            const float F = Kf[f] * imd[f];
            if (f == 0) {
                X0 = E;            X3 = F;
                X1 = E * C1[f];    X4 = F * C1[f];
                X2 = E * C2[f];    X5 = F * C2[f];
            } else {
                X0 += E;                      X3 += F;
                X1 = fmaf(E, C1[f], X1);      X4 = fmaf(F, C1[f], X4);
                X2 = fmaf(E, C2[f], X2);      X5 = fmaf(F, C2[f], X5);
            }
        }
        const float g6[6] = {X0, X1, X2, X3, X4, X5};

        // ---- butterfly reduce-scatter: 8 cols (6 real + 2 pad) ----
        float r4v[4];
        #pragma unroll
        for (int i = 0; i < 4; ++i) {            // mask 16, weight 4
            float x = g6[i];
            float y = (i + 4 < 6) ? g6[i + 4] : 0.0f;
            swap16(x, y);
            r4v[i] = x + y;
        }
        float r2v[2];
        #pragma unroll
        for (int i = 0; i < 2; ++i) {            // mask 32, weight 2
            float x = r4v[i], y = r4v[i + 2];
            swap32(x, y);
            r2v[i] = x + y;
        }
        float r1v;
        {                                         // mask 1 (DPP), weight 1
            const float x = r2v[0], y = r2v[1];
            const float P = up1 ? y : x, Q = up1 ? x : y;
            r1v = P + dpp_mov<0xB1>(Q);
        }
        r1v += dpp_mov<0x4E>(r1v);                // mask 2 full sum
        r1v += dpp_mov<0x128>(r1v);               // mask 8 full sum
        r1v += __shfl_xor(r1v, 4);                // mask 4 full sum

        // ---- extract the 6 moment sums (uniform), rebuild all gradients ----
        const float S0 = readlane_f(r1v, 0);      // col(0)=0  : sum E
        const float S1v = readlane_f(r1v, 1);     // col(1)=1  : sum E*C1
        const float S2v = readlane_f(r1v, 32);    // col(32)=2 : sum E*C2
        const float T0 = readlane_f(r1v, 33);     // col(33)=3 : sum F
        const float T1v = readlane_f(r1v, 16);    // col(16)=4 : sum F*C1
        const float T2v = readlane_f(r1v, 17);    // col(17)=5 : sum F*C2

        const float gb0 = fmaf(B0f, S0, fmaf(B1f, S1v, B2f * S2v));
        const float gb1 = fmaf(B0f + B2f, S1v, B1f * S0);
        const float gb2 = fmaf(B0f, S2v, fmaf(B1f, S1v, B2f * S0));
        const float ga0 = fmaf(A0f, T0, fmaf(A1f, T1v, A2f * T2v));
        const float ga1 = fmaf(A0f + A2f, T1v, A1f * T0);
        const float ga2 = fmaf(A0f, T2v, fmaf(A1f, T1v, A2f * T0));

        // b-side: true grad = +g -> minus; a-side: true grad = -g -> plus
        B0f = fmaf(-LRATE, gb0, B0f);
        B1f = fmaf(-LRATE, gb1, B1f);
        B2f = fmaf(-LRATE, gb2, B2f);
        A0f = fmaf( LRATE, ga0, A0f);
        A1f = fmaf( LRATE, ga1, A1f);
        A2f = fmaf( LRATE, ga2, A2f);
    }

    if (L == 0) {
        out[6 * w + 0] = B0f;
        out[6 * w + 1] = B1f;
        out[6 * w + 2] = B2f;
        out[6 * w + 3] = A0f;
        out[6 * w + 4] = A1f;
        out[6 * w + 5] = A2f;
    }
}

extern "C" void kernel_launch(void* const* d_in, const int* in_sizes, int n_in,
                              void* d_out, int out_size, void* d_ws, size_t ws_size,
                              hipStream_t stream) {
    const float* target   = (const float*)d_in[0];   // (512,)
    const float* sos_init = (const float*)d_in[1];   // (1,16,6) = 96
    float* out = (float*)d_out;                      // 96 floats
    hipLaunchKernelGGL(sgd_filter_design_kernel, dim3(1), dim3(1024), 0, stream,
                       target, sos_init, out);
}

// Round 10
// 1477.889 us; speedup vs baseline: 1.4921x; 1.0029x over previous
//
#include <hip/hip_runtime.h>
#include <math.h>

#define NITER 1000
#define LRATE 0.1f

typedef unsigned int v2u __attribute__((ext_vector_type(2)));

__device__ __forceinline__ float rcpf(float x) { return __builtin_amdgcn_rcpf(x); }

__device__ __forceinline__ float readlane_f(float v, int l) {
    return __int_as_float(__builtin_amdgcn_readlane(__float_as_int(v), l));
}

template<int CTRL>
__device__ __forceinline__ float dpp_mov(float v) {
    return __int_as_float(__builtin_amdgcn_update_dpp(0, __float_as_int(v), CTRL, 0xF, 0xF, true));
}

__device__ __forceinline__ int lane_id() {
    return __builtin_amdgcn_mbcnt_hi(~0u, __builtin_amdgcn_mbcnt_lo(~0u, 0u));
}

__device__ __forceinline__ void swap16(float& x, float& y) {
#if __has_builtin(__builtin_amdgcn_permlane16_swap)
    v2u r = __builtin_amdgcn_permlane16_swap(__float_as_uint(x), __float_as_uint(y), false, false);
    x = __uint_as_float(r[0]);
    y = __uint_as_float(r[1]);
#else
    const bool up = lane_id() & 16;
    const float send = up ? x : y;
    const float recv = __shfl_xor(send, 16);
    x = up ? recv : x;
    y = up ? y : recv;
#endif
}

__device__ __forceinline__ void swap32(float& x, float& y) {
#if __has_builtin(__builtin_amdgcn_permlane32_swap)
    v2u r = __builtin_amdgcn_permlane32_swap(__float_as_uint(x), __float_as_uint(y), false, false);
    x = __uint_as_float(r[0]);
    y = __uint_as_float(r[1]);
#else
    const bool up = lane_id() & 32;
    const float send = up ? x : y;
    const float recv = __shfl_xor(send, 32);
    x = up ? recv : x;
    y = up ? y : recv;
#endif
}

// One block, 1024 threads = 16 waves (4/SIMD). Wave w owns section w; all 6
// of its coefficients are wave-uniform scalars. Lane L owns freqs 8L..8L+7.
// Gradient via moment sums: with E=K/|num|^2, F=K/|den|^2 per freq,
//   S0=sum E, S1=sum E*cos(w), S2=sum E*cos(2w)   (T* for the a-side)
//   g_b0 = b0*S0 + b1*S1 + b2*S2
//   g_b1 = b1*S0 + (b0+b2)*S1
//   g_b2 = b2*S0 + b1*S1 + b0*S2      (uses cos(w)cos(2w)+sin(w)sin(2w)=cos(w))
// so only 6 values cross lanes; every lane then reconstructs all gradients.
//
// launch_bounds: second arg 1 (NOT 4) — a 1024-thread block already implies a
// 128-VGPR cap; requesting more residency starved the allocator to 44 VGPRs
// and forced per-iteration rematerialization of the trig constants (R9).
__global__ __launch_bounds__(1024, 1)
void sgd_filter_design_kernel(const float* __restrict__ target,
                              const float* __restrict__ sos_init,
                              float* __restrict__ out)
{
    const int t = threadIdx.x;
    const int w = t >> 6;
    const int L = t & 63;

    __shared__ __align__(16) float wq[16][576];
    __shared__ __align__(16) float Kbuf[576];

    // per-freq constants (f32 scalar, kept resident in VGPRs)
    const float PI = 3.14159265358979323846f;
    float C1[8], S1[8], C2[8], S2[8];
    #pragma unroll
    for (int f = 0; f < 8; ++f) {
        const int n = 8 * L + f;
        const float wr = PI * (float)n / 511.0f;
        const float c1 = cosf(wr), s1 = sinf(wr);
        C1[f] = c1; S1[f] = s1;
        C2[f] = 2.0f * c1 * c1 - 1.0f;
        S2[f] = 2.0f * s1 * c1;
    }

    float mKt = 0.0f;
    int kaddr = 0;
    if (t < 512) {
        mKt = -0.03392925639869154f * target[t];          // -ALPHA*tgt
        kaddr = 8 * (t >> 3) + 4 * (t >> 5) + (t & 7);    // swizzled
    }

    const int sw = 8 * L + 4 * (L >> 2);                  // 2-way = free
    const int col = ((L & 16) >> 2) | ((L & 32) >> 4) | (L & 1);
    const bool up1 = L & 1;

    // init coefficients as wave-uniform scalars
    float v0 = 0.0f;
    if (col < 6) v0 = sos_init[6 * w + col];
    float B0f = readlane_f(v0, 0);
    float B1f = readlane_f(v0, 1);
    float B2f = readlane_f(v0, 32);
    float A0f = readlane_f(v0, 33);
    float A1f = readlane_f(v0, 16);
    float A2f = readlane_f(v0, 17);

    for (int it = 0; it < NITER; ++it) {
        // ---- forward: own section at 8 freqs ----
        float imn[8], imd[8], qs[8];
        #pragma unroll
        for (int f = 0; f < 8; ++f) {
            const float nr = fmaf(B2f, C2[f], fmaf(B1f, C1[f], B0f));
            const float ni = fmaf(B2f, S2[f], B1f * S1[f]);   // = -Im(num)
            const float dr = fmaf(A2f, C2[f], fmaf(A1f, C1[f], A0f));
            const float di = fmaf(A2f, S2[f], A1f * S1[f]);   // = -Im(den)
            const float mn = fmaf(nr, nr, ni * ni);
            const float md = fmaf(dr, dr, di * di);
            const float rr = rcpf(mn * md);                    // one rcp
            const float iimd = rr * mn;                        // 1/md
            const float iimn = rr * md;                        // 1/mn
            qs[f] = mn * iimd;                                 // |num/den|^2
            imn[f] = iimn;
            imd[f] = iimd;
        }
        {
            const float4 q0 = {qs[0], qs[1], qs[2], qs[3]};
            const float4 q1 = {qs[4], qs[5], qs[6], qs[7]};
            *reinterpret_cast<float4*>(&wq[w][sw])     = q0;
            *reinterpret_cast<float4*>(&wq[w][sw + 4]) = q1;
        }
        __syncthreads();   // b1: wq ready; fences last iter's Kbuf reads

        // ---- single K-pass: one freq per thread (waves 0-7) ----
        if (t < 512) {
            float p[16];
            #pragma unroll
            for (int ww = 0; ww < 16; ++ww) p[ww] = wq[ww][kaddr];
            p[0] *= p[8];  p[1] *= p[9];  p[2] *= p[10]; p[3] *= p[11];
            p[4] *= p[12]; p[5] *= p[13]; p[6] *= p[14]; p[7] *= p[15];
            p[0] *= p[4];  p[1] *= p[5];  p[2] *= p[6];  p[3] *= p[7];
            p[0] *= p[2];  p[1] *= p[3];
            p[0] *= p[1];
            // K = 0.102137240*log2(q) - ALPHA*tgt
            Kbuf[kaddr] = fmaf(__log2f(p[0]), 0.10213724040f, mKt);
        }
        __syncthreads();   // b2: Kbuf ready

        const float4 k0 = *reinterpret_cast<const float4*>(&Kbuf[sw]);
        const float4 k1 = *reinterpret_cast<const float4*>(&Kbuf[sw + 4]);
        const float Kf[8] = {k0.x, k0.y, k0.z, k0.w, k1.x, k1.y, k1.z, k1.w};

        // ---- moment accumulation: 6 sums over own 8 freqs ----
        float X0, X1, X2, X3, X4, X5;
        #pragma unroll
        for (int f = 0; f < 8; ++f) {
            const float E = Kf[f] * imn[f];
            const float F = Kf[f] * imd[f];
            if (f == 0) {
                X0 = E;            X3 = F;
                X1 = E * C1[f];    X4 = F * C1[f];
                X2 = E * C2[f];    X5 = F * C2[f];
            } else {
                X0 += E;                      X3 += F;
                X1 = fmaf(E, C1[f], X1);      X4 = fmaf(F, C1[f], X4);
                X2 = fmaf(E, C2[f], X2);      X5 = fmaf(F, C2[f], X5);
            }
        }
        const float g6[6] = {X0, X1, X2, X3, X4, X5};

        // ---- butterfly reduce-scatter: 8 cols (6 real + 2 pad) ----
        float r4v[4];
        #pragma unroll
        for (int i = 0; i < 4; ++i) {            // mask 16, weight 4
            float x = g6[i];
            float y = (i + 4 < 6) ? g6[i + 4] : 0.0f;
            swap16(x, y);
            r4v[i] = x + y;
        }
        float r2v[2];
        #pragma unroll
        for (int i = 0; i < 2; ++i) {            // mask 32, weight 2
            float x = r4v[i], y = r4v[i + 2];
            swap32(x, y);
            r2v[i] = x + y;
        }
        float r1v;
        {                                         // mask 1 (DPP), weight 1
            const float x = r2v[0], y = r2v[1];
            const float P = up1 ? y : x, Q = up1 ? x : y;
            r1v = P + dpp_mov<0xB1>(Q);
        }
        r1v += dpp_mov<0x4E>(r1v);                // mask 2 full sum
        r1v += dpp_mov<0x128>(r1v);               // mask 8 full sum
        r1v += __shfl_xor(r1v, 4);                // mask 4 full sum

        // ---- extract the 6 moment sums (uniform), rebuild all gradients ----
        const float S0 = readlane_f(r1v, 0);      // col(0)=0  : sum E
        const float S1v = readlane_f(r1v, 1);     // col(1)=1  : sum E*C1
        const float S2v = readlane_f(r1v, 32);    // col(32)=2 : sum E*C2
        const float T0 = readlane_f(r1v, 33);     // col(33)=3 : sum F
        const float T1v = readlane_f(r1v, 16);    // col(16)=4 : sum F*C1
        const float T2v = readlane_f(r1v, 17);    // col(17)=5 : sum F*C2

        const float gb0 = fmaf(B0f, S0, fmaf(B1f, S1v, B2f * S2v));
        const float gb1 = fmaf(B0f + B2f, S1v, B1f * S0);
        const float gb2 = fmaf(B0f, S2v, fmaf(B1f, S1v, B2f * S0));
        const float ga0 = fmaf(A0f, T0, fmaf(A1f, T1v, A2f * T2v));
        const float ga1 = fmaf(A0f + A2f, T1v, A1f * T0);
        const float ga2 = fmaf(A0f, T2v, fmaf(A1f, T1v, A2f * T0));

        // b-side: true grad = +g -> minus; a-side: true grad = -g -> plus
        B0f = fmaf(-LRATE, gb0, B0f);
        B1f = fmaf(-LRATE, gb1, B1f);
        B2f = fmaf(-LRATE, gb2, B2f);
        A0f = fmaf( LRATE, ga0, A0f);
        A1f = fmaf( LRATE, ga1, A1f);
        A2f = fmaf( LRATE, ga2, A2f);
    }

    if (L == 0) {
        out[6 * w + 0] = B0f;
        out[6 * w + 1] = B1f;
        out[6 * w + 2] = B2f;
        out[6 * w + 3] = A0f;
        out[6 * w + 4] = A1f;
        out[6 * w + 5] = A2f;
    }
}

extern "C" void kernel_launch(void* const* d_in, const int* in_sizes, int n_in,
                              void* d_out, int out_size, void* d_ws, size_t ws_size,
                              hipStream_t stream) {
    const float* target   = (const float*)d_in[0];   // (512,)
    const float* sos_init = (const float*)d_in[1];   // (1,16,6) = 96
    float* out = (float*)d_out;                      // 96 floats
    hipLaunchKernelGGL(sgd_filter_design_kernel, dim3(1), dim3(1024), 0, stream,
                       target, sos_init, out);
}